// Round 12
// baseline (129.055 us; speedup 1.0000x reference)
//
#include <hip/hip_runtime.h>
#include <hip/hip_bf16.h>
#include <math.h>

#define B 128
#define C 2048
#define N 196
#define K 112
#define KB 113
#define MROWS 128
#define XWROW 113
#define NCLS 200
#define CKC (C * K)
#define NT 7            // 7 col-tiles of 32 per batch image
#define MAIN_BLKS 896   // 128 * 7, one wave each
#define PQ_BLKS 5600    // 22400 wids / 4

#define OUT1_OFF 2834944
#define OUT2_OFF 2849280

typedef __attribute__((ext_vector_type(8))) short bf16x8;
typedef __attribute__((ext_vector_type(4))) float f32x4;

__device__ inline unsigned cvtpk(float a, float b) {
    union { __hip_bfloat162 h; unsigned u; } c;
    c.h.x = __float2bfloat16(a);
    c.h.y = __float2bfloat16(b);
    return c.u;
}
__device__ inline const float* row_src(int row, const float* concepts,
                                       const float* background, const float* wcfc) {
    if (row < K) return concepts + (size_t)row * C;
    if (row == K) return background;
    if (row == XWROW) return wcfc;
    return nullptr;
}
// fire-and-forget global->LDS DMA: dest is wave-uniform base, HW adds lane*16
__device__ __forceinline__ void gl16(const void* g, void* l) {
    __builtin_amdgcn_global_load_lds(
        (const __attribute__((address_space(1))) unsigned*)g,
        (__attribute__((address_space(3))) unsigned*)l, 16, 0, 0);
}

// ---------------------------------------------------------------------------
__global__ __launch_bounds__(256)
void asq_kernel(const float* __restrict__ concepts, const float* __restrict__ background,
                const float* __restrict__ wcfc, float* __restrict__ asq) {
    const int row = blockIdx.x;
    const int tid = threadIdx.x;
    const float* src = row_src(row, concepts, background, wcfc);
    float local = 0.f;
    if (src) for (int i = tid; i < C; i += 256) { float v = src[i]; local += v * v; }
    for (int off = 32; off; off >>= 1) local += __shfl_down(local, off);
    __shared__ float red[4];
    if ((tid & 63) == 0) red[tid >> 6] = local;
    __syncthreads();
    if (tid == 0) asq[row] = red[0] + red[1] + red[2] + red[3];
}

// ---------------------------------------------------------------------------
// pack: Afrag[it 0..63][f 0..7][lane][8 bf16]; lane l of (it,f) holds
//       A[16f+(l&15)][32it+8(l>>4)+j]  — linear DMA-ready stream
// ---------------------------------------------------------------------------
__global__ __launch_bounds__(64)
void pack_kernel(const float* __restrict__ concepts, const float* __restrict__ background,
                 const float* __restrict__ wcfc, unsigned short* __restrict__ Afrag) {
    const int f = blockIdx.x;
    const int it = blockIdx.y;
    const int l = threadIdx.x;
    const int row = 16 * f + (l & 15);
    const int kb = 32 * it + 8 * (l >> 4);
    const float* src = row_src(row, concepts, background, wcfc);
    unsigned o[4] = {0u, 0u, 0u, 0u};
    if (src) {
        const float4 f0 = *reinterpret_cast<const float4*>(src + kb);
        const float4 f1 = *reinterpret_cast<const float4*>(src + kb + 4);
        o[0] = cvtpk(f0.x, f0.y); o[1] = cvtpk(f0.z, f0.w);
        o[2] = cvtpk(f1.x, f1.y); o[3] = cvtpk(f1.z, f1.w);
    }
    *reinterpret_cast<uint4*>(Afrag + (((size_t)it * 8 + f) * 64 + l) * 8) =
        make_uint4(o[0], o[1], o[2], o[3]);
}

// ---------------------------------------------------------------------------
// fused_kernel, 64 threads (ONE wave) per block, NO barriers:
//  blkid < MAIN_BLKS : dots[128][32] = A @ x_b[:, 32cols] via MFMA.
//    NBUF=3 LDS rings (A 3x8KB, x 3x4KB), counted vmcnt(12), stage-ahead 2.
//    Wave-private register softmax epilogue.
//  else : pq body, 4 wids per wave.
// ---------------------------------------------------------------------------
__global__ __launch_bounds__(64)
void fused_kernel(const float* __restrict__ x,
                  const unsigned short* __restrict__ Afrag,
                  const float* __restrict__ asq_g,
                  float* __restrict__ out0,
                  float* __restrict__ lpart,
                  const float* __restrict__ wlfc,
                  const float* __restrict__ concepts,
                  const float* __restrict__ modulation,
                  float* __restrict__ Rm, float* __restrict__ Qs) {
    __shared__ __align__(16) char smem[36864];   // A 3x8KB | x 3x4KB
    const int lane = threadIdx.x;
    const int blkid = blockIdx.x;

    if (blkid < MAIN_BLKS) {
        const int b = blkid / NT;
        const int nt = blkid - b * NT;
        const int n0 = nt * 32;
        const int lo = lane & 15, hi = lane >> 4;

        char* Abase = smem;             // 3 x 8KB
        char* Xbase = smem + 24576;     // 3 x 4KB

        // A stream: consecutive lanes -> consecutive 16B (coalesced 1KB per gl16)
        const char* agl = (const char*)Afrag + lane * 16;
        // x: lane covers k-row (lane>>3) of each 8-row group, 16B col-seg (lane&7)
        // per-lane clamp keeps reads in-bounds & finite for the tail tile
        const int segb_raw = n0 * 4 + (lane & 7) * 16;
        const int segb = segb_raw < (N - 4) * 4 ? segb_raw : (N - 4) * 4;
        const char* xgl = (const char*)x
            + ((size_t)b * C + (lane >> 3)) * N * 4 + segb;

        f32x4 acc[8][2];
#pragma unroll
        for (int f = 0; f < 8; ++f) {
            acc[f][0] = (f32x4){0.f, 0.f, 0.f, 0.f};
            acc[f][1] = (f32x4){0.f, 0.f, 0.f, 0.f};
        }
        float xs0 = 0.f, xs1 = 0.f;

#define STAGE(BUF) do {                                                         \
        _Pragma("unroll")                                                       \
        for (int i_ = 0; i_ < 8; ++i_)                                          \
            gl16(agl + i_ * 1024, Abase + (BUF) * 8192 + i_ * 1024);            \
        _Pragma("unroll")                                                       \
        for (int i_ = 0; i_ < 4; ++i_)                                          \
            gl16(xgl + (size_t)i_ * 8 * N * 4, Xbase + (BUF) * 4096 + i_ * 1024);\
        agl += 8192; xgl += (size_t)32 * N * 4;                                 \
    } while (0)

#define PIPE_WAIT(NSTR) do {                                                    \
        asm volatile("s_waitcnt vmcnt(" NSTR ")" ::: "memory");                 \
        __builtin_amdgcn_sched_barrier(0);                                      \
    } while (0)

#define CONS(BUF) do {                                                          \
        bf16x8 af[8];                                                           \
        _Pragma("unroll")                                                       \
        for (int f_ = 0; f_ < 8; ++f_)                                          \
            af[f_] = *reinterpret_cast<const bf16x8*>(                          \
                Abase + (BUF) * 8192 + f_ * 1024 + (lane << 4));                \
        float xv0[8], xv1[8];                                                   \
        _Pragma("unroll")                                                       \
        for (int j_ = 0; j_ < 8; ++j_) {                                        \
            xv0[j_] = *reinterpret_cast<const float*>(                          \
                Xbase + (BUF) * 4096 + ((hi * 8 + j_) << 7) + (lo << 2));       \
            xv1[j_] = *reinterpret_cast<const float*>(                          \
                Xbase + (BUF) * 4096 + ((hi * 8 + j_) << 7) + ((16 + lo) << 2));\
        }                                                                       \
        union { unsigned u[4]; bf16x8 v; } b0_, b1_;                            \
        _Pragma("unroll")                                                       \
        for (int p_ = 0; p_ < 4; ++p_) {                                        \
            b0_.u[p_] = cvtpk(xv0[2 * p_], xv0[2 * p_ + 1]);                    \
            b1_.u[p_] = cvtpk(xv1[2 * p_], xv1[2 * p_ + 1]);                    \
        }                                                                       \
        _Pragma("unroll")                                                       \
        for (int j_ = 0; j_ < 8; ++j_) {                                        \
            xs0 += xv0[j_] * xv0[j_];                                           \
            xs1 += xv1[j_] * xv1[j_];                                           \
        }                                                                       \
        _Pragma("unroll")                                                       \
        for (int f_ = 0; f_ < 8; ++f_) {                                        \
            acc[f_][0] = __builtin_amdgcn_mfma_f32_16x16x32_bf16(               \
                af[f_], b0_.v, acc[f_][0], 0, 0, 0);                            \
            acc[f_][1] = __builtin_amdgcn_mfma_f32_16x16x32_bf16(               \
                af[f_], b1_.v, acc[f_][1], 0, 0, 0);                            \
        }                                                                       \
    } while (0)

        STAGE(0); STAGE(1);                    // iters 0,1 in flight (24 loads)
        for (int tp = 0; tp < 20; ++tp) {      // iters 0..59
            PIPE_WAIT("12"); STAGE(2); CONS(0);
            PIPE_WAIT("12"); STAGE(0); CONS(1);
            PIPE_WAIT("12"); STAGE(1); CONS(2);
        }
        PIPE_WAIT("12"); STAGE(2); CONS(0);    // t=60, stage it62
        PIPE_WAIT("12"); STAGE(0); CONS(1);    // t=61, stage it63
        PIPE_WAIT("12"); CONS(2);              // t=62
        PIPE_WAIT("0");  CONS(0);              // t=63

        // ---- wave-private register epilogue ----
        float xsq0 = xs0 + __shfl_xor(xs0, 16); xsq0 += __shfl_xor(xsq0, 32);
        float xsq1 = xs1 + __shfl_xor(xs1, 16); xsq1 += __shfl_xor(xsq1, 32);
        // row 113 -> f=7, hi=0, rr=1 (lanes 0..15 hold it, col = lane)
        const float xw0 = __shfl(acc[7][0][1], lo);
        const float xw1 = __shfl(acc[7][1][1], lo);
        const bool cv0 = (n0 + lo) < N;
        const bool cv1 = (n0 + 16 + lo) < N;

        float m0 = -3.4e38f, m1 = -3.4e38f;
#pragma unroll
        for (int f = 0; f < 8; ++f)
#pragma unroll
            for (int rr = 0; rr < 4; ++rr) {
                const int r = 16 * f + 4 * hi + rr;
                const bool valid = (f < 7) | ((hi == 0) & (rr == 0));
                if (valid) {
                    const float aq = asq_g[r];
                    float L0 = -sqrtf(fmaxf(aq + xsq0 - 2.f * acc[f][0][rr], 0.f));
                    float L1 = -sqrtf(fmaxf(aq + xsq1 - 2.f * acc[f][1][rr], 0.f));
                    acc[f][0][rr] = L0; acc[f][1][rr] = L1;
                    m0 = fmaxf(m0, L0); m1 = fmaxf(m1, L1);
                }
            }
        float M0 = fmaxf(m0, __shfl_xor(m0, 16)); M0 = fmaxf(M0, __shfl_xor(M0, 32));
        float M1 = fmaxf(m1, __shfl_xor(m1, 16)); M1 = fmaxf(M1, __shfl_xor(M1, 32));
        float s0 = 0.f, s1 = 0.f;
#pragma unroll
        for (int f = 0; f < 8; ++f)
#pragma unroll
            for (int rr = 0; rr < 4; ++rr) {
                const bool valid = (f < 7) | ((hi == 0) & (rr == 0));
                const float e0 = valid ? __expf(acc[f][0][rr] - M0) : 0.f;
                const float e1 = valid ? __expf(acc[f][1][rr] - M1) : 0.f;
                acc[f][0][rr] = e0; acc[f][1][rr] = e1;
                s0 += e0; s1 += e1;
            }
        float S0 = s0 + __shfl_xor(s0, 16); S0 += __shfl_xor(S0, 32);
        float S1 = s1 + __shfl_xor(s1, 16); S1 += __shfl_xor(S1, 32);
        const float iv0 = 1.f / S0, iv1 = 1.f / S1;

        float* o0 = out0 + (size_t)b * KB * N + n0 + lo;
#pragma unroll
        for (int f = 0; f < 8; ++f)
#pragma unroll
            for (int rr = 0; rr < 4; ++rr) {
                const int r = 16 * f + 4 * hi + rr;
                const bool valid = (f < 7) | ((hi == 0) & (rr == 0));
                if (valid && cv0) o0[(size_t)r * N] = acc[f][0][rr] * iv0;
                if (valid && cv1) o0[(size_t)r * N + 16] = acc[f][1][rr] * iv1;
            }
#pragma unroll
        for (int f = 0; f < 7; ++f)
#pragma unroll
            for (int rr = 0; rr < 4; ++rr) {
                float pv = (cv0 ? acc[f][0][rr] * iv0 * xw0 : 0.f)
                         + (cv1 ? acc[f][1][rr] * iv1 * xw1 : 0.f);
                pv += __shfl_xor(pv, 1);
                pv += __shfl_xor(pv, 2);
                pv += __shfl_xor(pv, 4);
                pv += __shfl_xor(pv, 8);
                if (lo == 0)
                    lpart[((size_t)b * NT + nt) * K + 16 * f + 4 * hi + rr] = pv;
            }
    } else {
        // ---------------- pq body: 4 wids per wave ----------------
        const int wb = (blkid - MAIN_BLKS) * 4;
#pragma unroll
        for (int q = 0; q < 4; ++q) {
            const int wid = wb + q;
            const int o = wid / K;
            const int k = wid % K;
            const float4* wp = reinterpret_cast<const float4*>(wlfc + (size_t)o * CKC + (size_t)k * C);
            const float4* cp = reinterpret_cast<const float4*>(concepts + (size_t)k * C);
            const float4* mp = reinterpret_cast<const float4*>(modulation);
            float s1 = 0.f, s2 = 0.f;
#pragma unroll
            for (int it = 0; it < 8; ++it) {
                const int idx = it * 64 + lane;
                const float4 w4 = wp[idx];
                const float4 c4 = cp[idx];
                const float4 m4 = mp[idx];
                s1 += w4.x * c4.x + w4.y * c4.y + w4.z * c4.z + w4.w * c4.w;
                s2 += w4.x * m4.x + w4.y * m4.y + w4.z * m4.z + w4.w * m4.w;
            }
            for (int off = 32; off; off >>= 1) {
                s1 += __shfl_down(s1, off);
                s2 += __shfl_down(s2, off);
            }
            if (lane == 0) { Rm[wid] = s1 - s2; Qs[wid] = s2; }
        }
    }
}

// ---------------------------------------------------------------------------
__global__ __launch_bounds__(256)
void final_kernel(const float* __restrict__ lpart, const float* __restrict__ bcfc,
                  const float* __restrict__ Rm, const float* __restrict__ Qs,
                  const float* __restrict__ blfc,
                  float* __restrict__ out1, float* __restrict__ out2) {
    const int b = blockIdx.x;
    const int tid = threadIdx.x;
    __shared__ float g_s[K];
    if (tid < K) {
        const float* lp = lpart + (size_t)b * NT * K + tid;
        float v = bcfc[0];
#pragma unroll
        for (int t = 0; t < NT; ++t) v += lp[(size_t)t * K];
        const float g = 1.f / (1.f + __expf(-v));
        out1[b * K + tid] = g;
        g_s[tid] = g;
    }
    __syncthreads();
    if (tid < NCLS) {
        float acc = blfc[tid];
        const float* rp = Rm + (size_t)tid * K;
        const float* qp = Qs + (size_t)tid * K;
        for (int k = 0; k < K; ++k) acc = fmaf(g_s[k], rp[k], acc) + qp[k];
        out2[b * NCLS + tid] = acc;
    }
}

extern "C" void kernel_launch(void* const* d_in, const int* in_sizes, int n_in,
                              void* d_out, int out_size, void* d_ws, size_t ws_size,
                              hipStream_t stream) {
    const float* x          = (const float*)d_in[0];
    const float* concepts   = (const float*)d_in[1];
    const float* modulation = (const float*)d_in[2];
    const float* background = (const float*)d_in[3];
    const float* wcfc       = (const float*)d_in[4];
    const float* bcfc       = (const float*)d_in[5];
    const float* wlfc       = (const float*)d_in[6];
    const float* blfc       = (const float*)d_in[7];

    float* out  = (float*)d_out;
    float* out0 = out;
    float* out1 = out + OUT1_OFF;
    float* out2 = out + OUT2_OFF;

    float* ws    = (float*)d_ws;
    float* asq   = ws;                               // 128
    float* lpart = asq + MROWS;                      // 128*7*112 = 100352
    float* Rm    = lpart + (size_t)B * NT * K;       // 22400
    float* Qs    = Rm + NCLS * K;                    // 22400
    unsigned short* Afrag = (unsigned short*)(Qs + NCLS * K);  // 512KB

    asq_kernel<<<MROWS, 256, 0, stream>>>(concepts, background, wcfc, asq);
    pack_kernel<<<dim3(8, 64), 64, 0, stream>>>(concepts, background, wcfc, Afrag);
    fused_kernel<<<MAIN_BLKS + PQ_BLKS, 64, 0, stream>>>(
        x, Afrag, asq, out0, lpart, wlfc, concepts, modulation, Rm, Qs);
    final_kernel<<<B, 256, 0, stream>>>(lpart, bcfc, Rm, Qs, blfc, out1, out2);
}